// Round 8
// baseline (103.747 us; speedup 1.0000x reference)
//
#include <hip/hip_runtime.h>

typedef float f32x2 __attribute__((ext_vector_type(2)));

constexpr int BLOCK = 256;
constexpr int IPT   = 2;   // anchors per thread, packed as one f32x2 lane-pair
constexpr int BPB   = 8;   // all batches per block -> 512 identical-work blocks, 2/CU

// wave-uniform broadcast of lane `l`'s value: pure VALU, no memory, no waitcnt
__device__ __forceinline__ float bcastf(float v, int l) {
    return __int_as_float(__builtin_amdgcn_readlane(__float_as_int(v), l));
}

__global__ __launch_bounds__(BLOCK, 2) void assign_cls_label_kernel(
    const float4* __restrict__ anchors4,  // (B,N) float4: y,x,h,w (or y1,x1,y2,x2)
    const float4* __restrict__ gt4,       // (B,A) float4: y1,x1,y2,x2
    const int* __restrict__ gt_counts,    // (B,1)
    const int* __restrict__ use_anchor_p, // scalar
    int* __restrict__ out,                // (B,N)
    int N, int A, int B)
{
#pragma clang fp contract(off)
    const int tid   = threadIdx.x;
    const int lane  = tid & 63;
    const int n0r   = blockIdx.x * (BLOCK * IPT) + tid;   // lane-contiguous -> coalesced
    const int n1r   = n0r + BLOCK;
    const int n0    = (n0r < N) ? n0r : N - 1;            // tail clamp (stores guarded)
    const int n1    = (n1r < N) ? n1r : N - 1;
    const int b0    = blockIdx.y * BPB;
    const int glane = (lane < A) ? lane : A - 1;          // lane i holds gt box i

    // rolling prefetch for batch 0: anchors (per-lane) + gt boxes (per-lane staging)
    float4 an0  = anchors4[(size_t)b0 * N + n0];
    float4 an1  = anchors4[(size_t)b0 * N + n1];
    float4 nbox = gt4[(size_t)b0 * A + glane];

    const int   use_anchor = use_anchor_p[0];
    const float c26 = 1.0f / 67108864.0f;  // fl(i/u)>=0.5 <=> i-(0.5-2^-26)u >= 0 (sign-exact)

#pragma clang loop unroll(disable)
    for (int bb = 0; bb < BPB; ++bb) {
        if (b0 + bb >= B) break;                          // uniform
        const int count = gt_counts[b0 + bb];             // uniform scalar load

        const float4 ac0 = an0, ac1 = an1;
        const float4 cbox = nbox;
        if (bb + 1 < BPB && b0 + bb + 1 < B) {            // prefetch next batch
            an0  = anchors4[(size_t)(b0 + bb + 1) * N + n0];
            an1  = anchors4[(size_t)(b0 + bb + 1) * N + n1];
            nbox = gt4[(size_t)(b0 + bb + 1) * A + glane];
        }

        f32x2 Y1, X1, Y2, X2, AREA;
        if (use_anchor) {
            const f32x2 H  = {ac0.z, ac1.z};
            const f32x2 W  = {ac0.w, ac1.w};
            const f32x2 Yc = {ac0.x, ac1.x};
            const f32x2 Xc = {ac0.y, ac1.y};
            Y1 = Yc - H * 0.5f;    // h*0.5 exact; one rounded sub == ref's y - h/2
            Y2 = Y1 + H;
            X1 = Xc - W * 0.5f;
            X2 = X1 + W;
            AREA = H * W;
        } else {
            Y1 = f32x2{ac0.x, ac1.x}; X1 = f32x2{ac0.y, ac1.y};
            Y2 = f32x2{ac0.z, ac1.z}; X2 = f32x2{ac0.w, ac1.w};
            AREA = (Y2 - Y1) * (X2 - X1);
        }
        f32x2 ACC = {-1.0f, -1.0f};

        // per-lane gt area for this batch (same op order as ref; bit-identical to
        // computing it from the broadcast coords, since broadcast copies bits)
        const float cga = (cbox.z - cbox.x) * (cbox.w - cbox.y);

        auto comp = [&](float gy1, float gx1, float gy2, float gx2, float ga) {
            f32x2 yy1, yy2, xx1, xx2;
            yy1.x = __builtin_amdgcn_fmed3f(Y1.x, gy1, gy2);
            yy1.y = __builtin_amdgcn_fmed3f(Y1.y, gy1, gy2);
            yy2.x = __builtin_amdgcn_fmed3f(Y2.x, gy1, gy2);
            yy2.y = __builtin_amdgcn_fmed3f(Y2.y, gy1, gy2);
            xx1.x = __builtin_amdgcn_fmed3f(X1.x, gx1, gx2);
            xx1.y = __builtin_amdgcn_fmed3f(X1.y, gx1, gx2);
            xx2.x = __builtin_amdgcn_fmed3f(X2.x, gx1, gx2);
            xx2.y = __builtin_amdgcn_fmed3f(X2.y, gx1, gx2);
            const f32x2 dy    = yy2 - yy1;
            const f32x2 dx    = xx2 - xx1;
            const f32x2 inter = dy * dx;
            const f32x2 u     = (AREA + ga) - inter;      // ref assoc: (area+ga)-inter
            const f32x2 mh    = {-0.5f, -0.5f};
            const f32x2 cc    = {c26, c26};
            const f32x2 e = __builtin_elementwise_fma(u, mh, inter); // Sterbenz-exact band
            const f32x2 r = __builtin_elementwise_fma(u, cc, e);     // sign-exact decision
            ACC = __builtin_elementwise_max(ACC, r);
        };

        if (A <= 64) {
            // ZERO-memory inner loop: broadcast lane gi's staged box via v_readlane.
            // gi < count <= A <= 64, so the lane index is always valid.
            for (int gi = 0; gi < count; ++gi) {
                comp(bcastf(cbox.x, gi), bcastf(cbox.y, gi),
                     bcastf(cbox.z, gi), bcastf(cbox.w, gi), bcastf(cga, gi));
            }
        } else {
            // generic fallback (unused at A=64): uniform direct loads
            const float4* __restrict__ grow = gt4 + (size_t)(b0 + bb) * A;
            for (int gi = 0; gi < count; ++gi) {
                const float4 g = grow[gi];
                comp(g.x, g.y, g.z, g.w, (g.z - g.x) * (g.w - g.y));
            }
        }

        int* orow = out + (size_t)(b0 + bb) * N;
        if (n0r < N) orow[n0r] = (ACC.x >= 0.0f) ? 1 : 0;
        if (n1r < N) orow[n1r] = (ACC.y >= 0.0f) ? 1 : 0;
    }
}

extern "C" void kernel_launch(void* const* d_in, const int* in_sizes, int n_in,
                              void* d_out, int out_size, void* d_ws, size_t ws_size,
                              hipStream_t stream) {
    const float4* anchors4   = (const float4*)d_in[0];
    const float4* gt4        = (const float4*)d_in[1];
    const int*    gt_counts  = (const int*)d_in[2];
    const int*    use_anchor = (const int*)d_in[3];
    int*          out        = (int*)d_out;

    const int B = in_sizes[2];              // gt_counts is (B,1)
    const int A = in_sizes[1] / (4 * B);    // gt_bboxess is (B,A,4)
    const int N = in_sizes[0] / (4 * B);    // anchorss   is (B,N,4)

    dim3 grid((N + BLOCK * IPT - 1) / (BLOCK * IPT), (B + BPB - 1) / BPB);
    hipLaunchKernelGGL(assign_cls_label_kernel, grid, dim3(BLOCK), 0, stream,
                       anchors4, gt4, gt_counts, use_anchor, out, N, A, B);
}

// Round 9
// 101.326 us; speedup vs baseline: 1.0239x; 1.0239x over previous
//
#include <hip/hip_runtime.h>

typedef float f32x2 __attribute__((ext_vector_type(2)));

constexpr int BLOCK = 256;
constexpr int IPT   = 2;   // anchors per thread, packed as one f32x2 lane-pair

// wave-uniform broadcast of lane `l`'s value: pure VALU, no memory, no waitcnt
__device__ __forceinline__ float bcastf(float v, int l) {
    return __int_as_float(__builtin_amdgcn_readlane(__float_as_int(v), l));
}

__global__ __launch_bounds__(BLOCK, 8) void assign_cls_label_kernel(
    const float4* __restrict__ anchors4,  // (B,N) float4: y,x,h,w (or y1,x1,y2,x2)
    const float4* __restrict__ gt4,       // (B,A) float4: y1,x1,y2,x2
    const int* __restrict__ gt_counts,    // (B,1)
    const int* __restrict__ use_anchor_p, // scalar
    int* __restrict__ out,                // (B,N)
    int N, int A)
{
#pragma clang fp contract(off)
    const int tid   = threadIdx.x;
    const int lane  = tid & 63;
    const int b     = blockIdx.y;                         // one batch per block: full TLP
    const int n0r   = blockIdx.x * (BLOCK * IPT) + tid;   // lane-contiguous -> coalesced
    const int n1r   = n0r + BLOCK;
    const int n0    = (n0r < N) ? n0r : N - 1;            // tail clamp (stores guarded)
    const int n1    = (n1r < N) ? n1r : N - 1;
    const int glane = (lane < A) ? lane : A - 1;          // lane i holds gt box i

    // one coalesced load each; the only VMEM ops besides the final stores
    const float4 ac0  = anchors4[(size_t)b * N + n0];
    const float4 ac1  = anchors4[(size_t)b * N + n1];
    const float4 cbox = gt4[(size_t)b * A + glane];       // per-lane staged gt box
    const int    count      = gt_counts[b];               // uniform scalar load
    const int    use_anchor = use_anchor_p[0];

    const float c26 = 1.0f / 67108864.0f;  // fl(i/u)>=0.5 <=> i-(0.5-2^-26)u >= 0 (sign-exact)

    f32x2 Y1, X1, Y2, X2, AREA;
    if (use_anchor) {
        const f32x2 H  = {ac0.z, ac1.z};
        const f32x2 W  = {ac0.w, ac1.w};
        const f32x2 Yc = {ac0.x, ac1.x};
        const f32x2 Xc = {ac0.y, ac1.y};
        Y1 = Yc - H * 0.5f;    // h*0.5 exact; one rounded sub == ref's y - h/2
        Y2 = Y1 + H;
        X1 = Xc - W * 0.5f;
        X2 = X1 + W;
        AREA = H * W;
    } else {
        Y1 = f32x2{ac0.x, ac1.x}; X1 = f32x2{ac0.y, ac1.y};
        Y2 = f32x2{ac0.z, ac1.z}; X2 = f32x2{ac0.w, ac1.w};
        AREA = (Y2 - Y1) * (X2 - X1);
    }
    f32x2 ACC = {-1.0f, -1.0f};

    // per-lane gt area (ref op order); broadcast copies bits, so identical to ref's ga
    const float cga = (cbox.z - cbox.x) * (cbox.w - cbox.y);

    auto comp = [&](float gy1, float gx1, float gy2, float gx2, float ga) {
        f32x2 yy1, yy2, xx1, xx2;
        yy1.x = __builtin_amdgcn_fmed3f(Y1.x, gy1, gy2);
        yy1.y = __builtin_amdgcn_fmed3f(Y1.y, gy1, gy2);
        yy2.x = __builtin_amdgcn_fmed3f(Y2.x, gy1, gy2);
        yy2.y = __builtin_amdgcn_fmed3f(Y2.y, gy1, gy2);
        xx1.x = __builtin_amdgcn_fmed3f(X1.x, gx1, gx2);
        xx1.y = __builtin_amdgcn_fmed3f(X1.y, gx1, gx2);
        xx2.x = __builtin_amdgcn_fmed3f(X2.x, gx1, gx2);
        xx2.y = __builtin_amdgcn_fmed3f(X2.y, gx1, gx2);
        const f32x2 dy    = yy2 - yy1;
        const f32x2 dx    = xx2 - xx1;
        const f32x2 inter = dy * dx;
        const f32x2 u     = (AREA + ga) - inter;          // ref assoc: (area+ga)-inter
        const f32x2 mh    = {-0.5f, -0.5f};
        const f32x2 cc    = {c26, c26};
        const f32x2 e = __builtin_elementwise_fma(u, mh, inter);  // Sterbenz-exact band
        const f32x2 r = __builtin_elementwise_fma(u, cc, e);      // sign-exact decision
        ACC = __builtin_elementwise_max(ACC, r);
    };

    if (A <= 64) {
        // ZERO-memory inner loop: broadcast lane gi's staged box via v_readlane.
        // gi < count <= A <= 64, so the lane index is always valid.
        for (int gi = 0; gi < count; ++gi) {
            comp(bcastf(cbox.x, gi), bcastf(cbox.y, gi),
                 bcastf(cbox.z, gi), bcastf(cbox.w, gi), bcastf(cga, gi));
        }
    } else {
        // generic fallback (unused at A=64): uniform direct loads
        const float4* __restrict__ grow = gt4 + (size_t)b * A;
        for (int gi = 0; gi < count; ++gi) {
            const float4 g = grow[gi];
            comp(g.x, g.y, g.z, g.w, (g.z - g.x) * (g.w - g.y));
        }
    }

    int* orow = out + (size_t)b * N;
    if (n0r < N) orow[n0r] = (ACC.x >= 0.0f) ? 1 : 0;
    if (n1r < N) orow[n1r] = (ACC.y >= 0.0f) ? 1 : 0;
}

extern "C" void kernel_launch(void* const* d_in, const int* in_sizes, int n_in,
                              void* d_out, int out_size, void* d_ws, size_t ws_size,
                              hipStream_t stream) {
    const float4* anchors4   = (const float4*)d_in[0];
    const float4* gt4        = (const float4*)d_in[1];
    const int*    gt_counts  = (const int*)d_in[2];
    const int*    use_anchor = (const int*)d_in[3];
    int*          out        = (int*)d_out;

    const int B = in_sizes[2];              // gt_counts is (B,1)
    const int A = in_sizes[1] / (4 * B);    // gt_bboxess is (B,A,4)
    const int N = in_sizes[0] / (4 * B);    // anchorss   is (B,N,4)

    dim3 grid((N + BLOCK * IPT - 1) / (BLOCK * IPT), B);
    hipLaunchKernelGGL(assign_cls_label_kernel, grid, dim3(BLOCK), 0, stream,
                       anchors4, gt4, gt_counts, use_anchor, out, N, A);
}